// Round 1
// baseline (334.548 us; speedup 1.0000x reference)
//
#include <hip/hip_runtime.h>

#define D      8192
#define K      1024
#define BLOCK  256
#define SCALE  0.011048543456039806f   // 1/sqrt(8192)

// XOR-swizzle LDS physical address: bits [3:8) ^= bits [8:13).
// Bijective; keeps 8-float chunks contiguous & 16B-aligned.
__device__ __forceinline__ int swz(int i) {
    return i ^ (((i >> 8) & 31) << 3);
}

__device__ __forceinline__ void fwht32(float* x) {
#pragma unroll
    for (int s = 0; s < 5; ++s) {
        const int h = 1 << s;
#pragma unroll
        for (int g = 0; g < 32; g += 2 * h)
#pragma unroll
            for (int e = 0; e < h; ++e) {
                float a = x[g + e], b = x[g + e + h];
                x[g + e]     = a + b;
                x[g + e + h] = a - b;
            }
    }
}

__device__ __forceinline__ void fwht8(float* x) {
#pragma unroll
    for (int s = 0; s < 3; ++s) {
        const int h = 1 << s;
#pragma unroll
        for (int g = 0; g < 8; g += 2 * h)
#pragma unroll
            for (int e = 0; e < h; ++e) {
                float a = x[g + e], b = x[g + e + h];
                x[g + e]     = a + b;
                x[g + e + h] = a - b;
            }
    }
}

__global__ __launch_bounds__(BLOCK, 4)
void UpProjectFastHadamardTransform_80101140070867_kernel(
    const float* __restrict__ u, const int* __restrict__ idx,
    float* __restrict__ out)
{
    __shared__ float lds[D];
    const int row = blockIdx.x;
    const int t   = threadIdx.x;

    // ---- zero LDS (vectorized, physical-linear: swizzle-agnostic) ----
    float4* lds4 = (float4*)lds;
#pragma unroll
    for (int j = 0; j < D / 4 / BLOCK; ++j)          // 8 iters
        lds4[t + j * BLOCK] = make_float4(0.f, 0.f, 0.f, 0.f);
    __syncthreads();

    // ---- scatter u[row, :] into LDS at idx (duplicates accumulate) ----
    {
        const float4* urow4 = (const float4*)(u + (size_t)row * K);
        const int4*   idx4  = (const int4*)idx;
        float4 v  = urow4[t];                         // K/4 == BLOCK
        int4   id = idx4[t];
        atomicAdd(&lds[swz(id.x)], v.x);
        atomicAdd(&lds[swz(id.y)], v.y);
        atomicAdd(&lds[swz(id.z)], v.z);
        atomicAdd(&lds[swz(id.w)], v.w);
    }
    __syncthreads();

    float x[32];

    // ---- Phase 1: butterfly bits 0-4; thread t owns i = t*32 + j ----
#pragma unroll
    for (int g = 0; g < 4; ++g) {
        const int p = swz(t * 32 + g * 8);
        float4 a = *(const float4*)&lds[p];
        float4 b = *(const float4*)&lds[p + 4];
        x[g * 8 + 0] = a.x; x[g * 8 + 1] = a.y; x[g * 8 + 2] = a.z; x[g * 8 + 3] = a.w;
        x[g * 8 + 4] = b.x; x[g * 8 + 5] = b.y; x[g * 8 + 6] = b.z; x[g * 8 + 7] = b.w;
    }
    fwht32(x);
#pragma unroll
    for (int g = 0; g < 4; ++g) {
        const int p = swz(t * 32 + g * 8);
        *(float4*)&lds[p]     = make_float4(x[g*8+0], x[g*8+1], x[g*8+2], x[g*8+3]);
        *(float4*)&lds[p + 4] = make_float4(x[g*8+4], x[g*8+5], x[g*8+6], x[g*8+7]);
    }
    __syncthreads();

    // ---- Phase 2: butterfly bits 5-9; i = hi3*1024 + r*32 + lo5 ----
    {
        const int hi3 = t >> 5, lo5 = t & 31;
        const int base = hi3 * 1024 + lo5;
#pragma unroll
        for (int r = 0; r < 32; ++r) x[r] = lds[swz(base + r * 32)];
        fwht32(x);
#pragma unroll
        for (int r = 0; r < 32; ++r) lds[swz(base + r * 32)] = x[r];
    }
    __syncthreads();

    // ---- Phase 3: butterfly bits 10-12; i = r*1024 + g*256 + t; fused store ----
#pragma unroll
    for (int g = 0; g < 4; ++g)
#pragma unroll
        for (int r = 0; r < 8; ++r)
            x[g * 8 + r] = lds[swz(r * 1024 + g * 256 + t)];
#pragma unroll
    for (int g = 0; g < 4; ++g) fwht8(&x[g * 8]);

    float* orow = out + (size_t)row * D;
#pragma unroll
    for (int g = 0; g < 4; ++g)
#pragma unroll
        for (int r = 0; r < 8; ++r)
            orow[r * 1024 + g * 256 + t] = x[g * 8 + r] * SCALE;  // lane-coalesced dwords
}

extern "C" void kernel_launch(void* const* d_in, const int* in_sizes, int n_in,
                              void* d_out, int out_size, void* d_ws, size_t ws_size,
                              hipStream_t stream) {
    const float* u   = (const float*)d_in[0];
    const int*   idx = (const int*)d_in[1];
    float*       out = (float*)d_out;
    const int rows = in_sizes[0] / K;   // 8192
    hipLaunchKernelGGL(UpProjectFastHadamardTransform_80101140070867_kernel,
                       dim3(rows), dim3(BLOCK), 0, stream, u, idx, out);
}

// Round 2
// 302.155 us; speedup vs baseline: 1.1072x; 1.1072x over previous
//
#include <hip/hip_runtime.h>

#define D      8192
#define K      1024
#define BLOCK  256
#define SCALE  0.011048543456039806f   // 1/sqrt(8192)

// Swizzle at float4 granularity: phys4 = f ^ ((f>>3)&7).
// Verified: all phase reads (contiguous-32-per-thread as 8x b128) and all
// transposed writes (stride-256 b32) land <=2 lanes/bank (free per m136).
__device__ __forceinline__ int swz4(int f) { return f ^ ((f >> 3) & 7); }

__device__ __forceinline__ void fwht32(float* x) {
#pragma unroll
    for (int s = 0; s < 5; ++s) {
        const int h = 1 << s;
#pragma unroll
        for (int g = 0; g < 32; g += 2 * h)
#pragma unroll
            for (int e = 0; e < h; ++e) {
                float a = x[g + e], b = x[g + e + h];
                x[g + e]     = a + b;
                x[g + e + h] = a - b;
            }
    }
}

__device__ __forceinline__ void fwht8(float* x) {
#pragma unroll
    for (int s = 0; s < 3; ++s) {
        const int h = 1 << s;
#pragma unroll
        for (int g = 0; g < 8; g += 2 * h)
#pragma unroll
            for (int e = 0; e < h; ++e) {
                float a = x[g + e], b = x[g + e + h];
                x[g + e]     = a + b;
                x[g + e + h] = a - b;
            }
    }
}

// Bit bookkeeping (orig index i = b12..b0):
//  L0 (post-scatter) = i.            P1 thread t: reads words [t*32,t*32+32)
//     -> transforms b0..b4, writes x[j] to L1 = (j<<8)|t.
//  L1 bits 0..7 = b5..b12, bits 8..12 = b0..b4.   P2 thread t: reads
//     [t*32,..) -> transforms b5..b9, writes to L2 = (m<<8)|t.
//  L2 bits: k=L2&31 -> (b10,b11,b12,b0,b1); t2=L2>>5 -> (b2..b4, b5..b9).
//     P3: 4x fwht8 over k&7 (=b10..b12), then float4 store:
//     i = g | (t&7)<<2 | (t>>3)<<5 | e<<10,  g = k>>3, e = k&7.
__global__ __launch_bounds__(BLOCK, 5)
void UpProjectFastHadamardTransform_80101140070867_kernel(
    const float* __restrict__ u, const int* __restrict__ idx,
    float* __restrict__ out)
{
    __shared__ float4 lds4[D / 4];
    float* lds = (float*)lds4;
    const int row = blockIdx.x;
    const int t   = threadIdx.x;

    // issue global loads first (overlap with LDS zero-fill)
    const float4 v  = ((const float4*)(u + (size_t)row * K))[t];
    const int4   id = ((const int4*)idx)[t];

    // zero LDS (physical-linear float4: swizzle-agnostic, conflict-free)
#pragma unroll
    for (int j = 0; j < D / 4 / BLOCK; ++j)
        lds4[t + j * BLOCK] = make_float4(0.f, 0.f, 0.f, 0.f);
    __syncthreads();

    // scatter-add (duplicate idx accumulate); logical word w -> phys word
    {
        int f, a;
        f = id.x >> 2; a = 4 * swz4(f) + (id.x & 3); atomicAdd(&lds[a], v.x);
        f = id.y >> 2; a = 4 * swz4(f) + (id.y & 3); atomicAdd(&lds[a], v.y);
        f = id.z >> 2; a = 4 * swz4(f) + (id.z & 3); atomicAdd(&lds[a], v.z);
        f = id.w >> 2; a = 4 * swz4(f) + (id.w & 3); atomicAdd(&lds[a], v.w);
    }
    __syncthreads();

    float x[32];
    const int c  = t & 7;                                   // swz4 xor for f=t*8+g
    const int wb = 4 * ((t >> 2) ^ ((t >> 5) & 7)) + (t & 3); // transposed-write base

    // ---- Phase 1: bits 0-4 ----
#pragma unroll
    for (int g = 0; g < 8; ++g) {
        float4 a = lds4[t * 8 + (g ^ c)];
        x[4*g+0] = a.x; x[4*g+1] = a.y; x[4*g+2] = a.z; x[4*g+3] = a.w;
    }
    fwht32(x);
    __syncthreads();                         // all reads done before overwrite
#pragma unroll
    for (int j = 0; j < 32; ++j) lds[j * 256 + wb] = x[j];  // -> L1 (transposed)
    __syncthreads();

    // ---- Phase 2: bits 5-9 ----
#pragma unroll
    for (int g = 0; g < 8; ++g) {
        float4 a = lds4[t * 8 + (g ^ c)];
        x[4*g+0] = a.x; x[4*g+1] = a.y; x[4*g+2] = a.z; x[4*g+3] = a.w;
    }
    fwht32(x);
    __syncthreads();
#pragma unroll
    for (int j = 0; j < 32; ++j) lds[j * 256 + wb] = x[j];  // -> L2 (transposed)
    __syncthreads();

    // ---- Phase 3: bits 10-12, fused with store ----
#pragma unroll
    for (int g = 0; g < 8; ++g) {
        float4 a = lds4[t * 8 + (g ^ c)];
        x[4*g+0] = a.x; x[4*g+1] = a.y; x[4*g+2] = a.z; x[4*g+3] = a.w;
    }
#pragma unroll
    for (int g2 = 0; g2 < 4; ++g2) fwht8(&x[g2 * 8]);

    float* orow = out + (size_t)row * D + ((t >> 3) * 32 + (t & 7) * 4);
#pragma unroll
    for (int e = 0; e < 8; ++e) {
        float4 o = make_float4(x[e] * SCALE, x[8 + e] * SCALE,
                               x[16 + e] * SCALE, x[24 + e] * SCALE);
        *(float4*)(orow + e * 1024) = o;     // wave-contiguous 1KB segments
    }
}

extern "C" void kernel_launch(void* const* d_in, const int* in_sizes, int n_in,
                              void* d_out, int out_size, void* d_ws, size_t ws_size,
                              hipStream_t stream) {
    const float* u   = (const float*)d_in[0];
    const int*   idx = (const int*)d_in[1];
    float*       out = (float*)d_out;
    const int rows = in_sizes[0] / K;   // 8192
    hipLaunchKernelGGL(UpProjectFastHadamardTransform_80101140070867_kernel,
                       dim3(rows), dim3(BLOCK), 0, stream, u, idx, out);
}